// Round 13
// baseline (944.574 us; speedup 1.0000x reference)
//
#include <hip/hip_runtime.h>
#include <math.h>

#define LEAKY 0.2f
#define BN_EPS 1e-5f

typedef unsigned short u16;
typedef __bf16 bf16x8 __attribute__((ext_vector_type(8)));
typedef float f32x4 __attribute__((ext_vector_type(4)));
typedef u16 ushort8 __attribute__((ext_vector_type(8)));

__device__ __forceinline__ u16 f2bf(float x){
    unsigned u = __float_as_uint(x);
    u += 0x7FFFu + ((u >> 16) & 1u);          // RNE (finite data, no NaN)
    return (u16)(u >> 16);
}
__device__ __forceinline__ float bf2f(u16 b){ return __uint_as_float(((unsigned)b) << 16); }

// ---------------- encoder ----------------

__global__ __launch_bounds__(256) void k_encoder(const float* __restrict__ x,
        const float* __restrict__ W, const float* __restrict__ b,
        float* __restrict__ z, int N){
    int gid = blockIdx.x*256 + threadIdx.x;
    int n = gid >> 6, j = gid & 63;
    if (n >= N) return;
    float acc = b[j];
    #pragma unroll
    for (int k=0;k<7;k++) acc += x[n*7+k]*W[k*64+j];
    z[(size_t)n*64+j] = acc;
}

// pack W[K][MW] fp32 -> hi/lo bf16 in MFMA B-fragment layout with MT col stride
template<int K, int MW, int MT>
__global__ __launch_bounds__(256) void k_pack_w(const float* __restrict__ W,
        u16* __restrict__ hi, u16* __restrict__ lo){
    int idx = blockIdx.x*256 + threadIdx.x;
    if (idx >= K*MW) return;
    int e = idx & 7, l16 = (idx >> 3) & 3, rest = idx >> 5;
    int n = rest % MW, t = rest / MW;
    int k = t*32 + l16*8 + e;
    float w = W[(size_t)k*MW + n];
    u16 hb = f2bf(w);
    size_t o = ((size_t)(t*MT + n)*4 + (size_t)l16)*8 + e;
    hi[o] = hb;
    lo[o] = f2bf(w - bf2f(hb));
}

// pack augmented attention columns: col MW+j (j<2H) = W[:,head block] . a_{src|dst}
template<int K, int MW, int MT, int H, int C>
__global__ __launch_bounds__(256) void k_pack_a(const float* __restrict__ W,
        const float* __restrict__ as, const float* __restrict__ ad,
        u16* __restrict__ hi, u16* __restrict__ lo){
    int idx = blockIdx.x*256 + threadIdx.x;
    if (idx >= K*16) return;
    int e = idx & 7, l16 = (idx >> 3) & 3, rest = idx >> 5;
    int j = rest % 16, t = rest / 16;
    int k = t*32 + l16*8 + e;
    float v = 0.f;
    if (j < 2*H){
        int hh = j >> 1;
        const float* a = (j & 1) ? ad : as;
        for (int c = 0; c < C; c++)
            v += W[(size_t)k*MW + hh*C + c] * a[hh*C + c];
    }
    u16 hb = f2bf(v);
    size_t o = ((size_t)(t*MT + MW + j)*4 + (size_t)l16)*8 + e;
    hi[o] = hb;
    lo[o] = f2bf(v - bf2f(hb));
}

// BN coefs: scale = gamma*rsqrt(var+eps); shift = beta - mu*scale
__global__ void k_bn_coef(const float* __restrict__ cs, const float* __restrict__ cq,
        const float* __restrict__ g, const float* __restrict__ be,
        float* __restrict__ scale, float* __restrict__ shift, float invN){
    int j = threadIdx.x;   // 128
    float mu = cs[j]*invN;
    float var = cq[j]*invN - mu*mu;
    float s = g[j]*rsqrtf(var + BN_EPS);
    scale[j] = s; shift[j] = be[j] - mu*s;
}

// ---------------- per-head global max of al_s (two-pass, no atomics) ----------------

template<int H>
__global__ __launch_bounds__(256) void k_mh1(const float* __restrict__ al,
        float* __restrict__ pm, int total){
    int t = threadIdx.x;
    float m = -1e30f;
    for (int i = blockIdx.x*256 + t; i < total; i += 64*256)
        m = fmaxf(m, al[i]);
    #pragma unroll
    for (int off = H; off < 64; off <<= 1)
        m = fmaxf(m, __shfl_xor(m, off, 64));
    __shared__ float ws[16];
    int lane = t & 63, wid = t >> 6;
    if (lane < H) ws[wid*H + lane] = m;
    __syncthreads();
    if (t < H){
        float mm = ws[t];
        #pragma unroll
        for (int w = 1; w < 4; w++) mm = fmaxf(mm, ws[w*H + t]);
        pm[blockIdx.x*H + t] = mm;
    }
}

template<int H>
__global__ void k_mh2(const float* __restrict__ pm, float* __restrict__ mh){
    int t = threadIdx.x;   // 64 threads
    float m = -1e30f;
    #pragma unroll
    for (int k = 0; k < H; k++) m = fmaxf(m, pm[t + k*64]);
    #pragma unroll
    for (int off = H; off < 64; off <<= 1)
        m = fmaxf(m, __shfl_xor(m, off, 64));
    if (t < H) mh[t] = m;
}

// split-bf16 MFMA GEMM, fused input-BN+ReLU (staging, XOR-swizzled LDS),
// attention logits via augmented B columns (no shuffle epilogue);
// writes h as bf16. No atomics.
template<int K, int MW, int RW, int CW, int WR, int WC, int H, bool BNIN>
__global__ __launch_bounds__(256) void k_gemm(const float* __restrict__ z,
        const u16* __restrict__ Whi, const u16* __restrict__ Wlo,
        const float* __restrict__ bnscale, const float* __restrict__ bnshift,
        u16* __restrict__ hout, float* __restrict__ al_s, float* __restrict__ al_d,
        int N)
{
    static_assert(RW*CW == 4 && RW*WR*16 == 64 && CW*WC*16 == MW, "tile config");
    constexpr int MT = MW + 16;    // packed stride incl. augmented cols
    constexpr int KS = K/32;
    constexpr int KG = K/8;
    __shared__ __align__(16) u16 Ahi[64*K];
    __shared__ __align__(16) u16 Alo[64*K];
    const int brow = blockIdx.x*64;
    const int tid = threadIdx.x;

    for (int u = tid; u < 64*KG; u += 256){
        int row = u / KG, kg = u % KG;
        int gr = brow + row;
        float v[8];
        if (gr < N){
            const float4* p = (const float4*)(z + (size_t)gr*K + kg*8);
            float4 a = p[0], bq = p[1];
            v[0]=a.x; v[1]=a.y; v[2]=a.z; v[3]=a.w;
            v[4]=bq.x; v[5]=bq.y; v[6]=bq.z; v[7]=bq.w;
            if (BNIN){
                const float4* sc = (const float4*)(bnscale + kg*8);
                const float4* sh = (const float4*)(bnshift + kg*8);
                float4 s0=sc[0], s1=sc[1], t0=sh[0], t1=sh[1];
                v[0]=fmaxf(fmaf(v[0],s0.x,t0.x),0.f);
                v[1]=fmaxf(fmaf(v[1],s0.y,t0.y),0.f);
                v[2]=fmaxf(fmaf(v[2],s0.z,t0.z),0.f);
                v[3]=fmaxf(fmaf(v[3],s0.w,t0.w),0.f);
                v[4]=fmaxf(fmaf(v[4],s1.x,t1.x),0.f);
                v[5]=fmaxf(fmaf(v[5],s1.y,t1.y),0.f);
                v[6]=fmaxf(fmaf(v[6],s1.z,t1.z),0.f);
                v[7]=fmaxf(fmaf(v[7],s1.w,t1.w),0.f);
            }
        } else {
            #pragma unroll
            for (int e=0;e<8;e++) v[e]=0.f;
        }
        ushort8 h8, l8;
        #pragma unroll
        for (int e=0;e<8;e++){
            u16 hb = f2bf(v[e]);
            h8[e] = hb;
            l8[e] = f2bf(v[e] - bf2f(hb));
        }
        int rb = row >> 4, t = kg >> 2, lg = kg & 3;
        int gidx = (rb*KS + t)*64 + (row & 15) + 16*lg;
        gidx ^= (gidx >> 4) & 7;                 // bank-conflict swizzle
        *(ushort8*)&Ahi[gidx*8] = h8;
        *(ushort8*)&Alo[gidx*8] = l8;
    }
    __syncthreads();

    const int wave = tid >> 6, lane = tid & 63;
    const int wrow = wave / CW, wcol = wave % CW;
    const int l15 = lane & 15, l16 = lane >> 4;

    f32x4 acc[WR][WC];
    f32x4 acc_e[WR];
    #pragma unroll
    for (int r=0;r<WR;r++){
        acc_e[r] = (f32x4){0.f,0.f,0.f,0.f};
        #pragma unroll
        for (int c=0;c<WC;c++) acc[r][c] = (f32x4){0.f,0.f,0.f,0.f};
    }

    #pragma unroll
    for (int t = 0; t < KS; ++t){
        bf16x8 ah[WR], al[WR];
        #pragma unroll
        for (int r=0;r<WR;r++){
            int rb = wrow*WR + r;
            int goff = (rb*KS + t)*64 + lane;
            goff ^= (goff >> 4) & 7;             // matching swizzle
            ah[r] = *(const bf16x8*)&Ahi[goff*8];
            al[r] = *(const bf16x8*)&Alo[goff*8];
        }
        bf16x8 bh[WC], bl[WC];
        #pragma unroll
        for (int c=0;c<WC;c++){
            int n = (wcol*WC + c)*16 + l15;
            size_t off = ((size_t)(t*MT + n)*4 + (size_t)l16)*8;
            bh[c] = *(const bf16x8*)&Whi[off];
            bl[c] = *(const bf16x8*)&Wlo[off];
        }
        #pragma unroll
        for (int r=0;r<WR;r++)
            #pragma unroll
            for (int c=0;c<WC;c++){
                acc[r][c] = __builtin_amdgcn_mfma_f32_16x16x32_bf16(al[r], bh[c], acc[r][c], 0,0,0);
                acc[r][c] = __builtin_amdgcn_mfma_f32_16x16x32_bf16(ah[r], bl[c], acc[r][c], 0,0,0);
                acc[r][c] = __builtin_amdgcn_mfma_f32_16x16x32_bf16(ah[r], bh[c], acc[r][c], 0,0,0);
            }
        if (wcol == 0){                           // augmented logit columns
            size_t offE = ((size_t)(t*MT + MW + l15)*4 + (size_t)l16)*8;
            bf16x8 bhe = *(const bf16x8*)&Whi[offE];
            bf16x8 ble = *(const bf16x8*)&Wlo[offE];
            #pragma unroll
            for (int r=0;r<WR;r++){
                acc_e[r] = __builtin_amdgcn_mfma_f32_16x16x32_bf16(al[r], bhe, acc_e[r], 0,0,0);
                acc_e[r] = __builtin_amdgcn_mfma_f32_16x16x32_bf16(ah[r], ble, acc_e[r], 0,0,0);
                acc_e[r] = __builtin_amdgcn_mfma_f32_16x16x32_bf16(ah[r], bhe, acc_e[r], 0,0,0);
            }
        }
    }

    // logits: lane l15 = j holds the complete dot for its rows — direct store
    if (wcol == 0 && l15 < 2*H){
        int j = l15;
        #pragma unroll
        for (int r=0;r<WR;r++)
            #pragma unroll
            for (int q=0;q<4;q++){
                int rowg = brow + (wrow*WR + r)*16 + l16*4 + q;
                if (rowg < N){
                    float v = acc_e[r][q];
                    if (H==4){
                        if (j & 1) al_d[(size_t)rowg*4 + (j>>1)] = v;
                        else       al_s[(size_t)rowg*4 + (j>>1)] = v;
                    } else {
                        if (j & 1) al_d[rowg] = v;
                        else       al_s[rowg] = v;
                    }
                }
            }
    }

    // h write (bf16)
    #pragma unroll
    for (int r=0;r<WR;r++)
        #pragma unroll
        for (int c=0;c<WC;c++){
            int colg = (wcol*WC + c)*16 + l15;
            #pragma unroll
            for (int q=0;q<4;q++){
                int rowg = brow + (wrow*WR + r)*16 + l16*4 + q;
                if (rowg < N) hout[(size_t)rowg*MW + colg] = f2bf(acc[r][c][q]);
            }
        }
}

// ---------------- CSR build (once per call) ----------------

__global__ __launch_bounds__(256) void k_deg(const int* __restrict__ ei, int E,
        int* __restrict__ deg){
    int e = blockIdx.x*256 + threadIdx.x;
    if (e < E) atomicAdd(deg + ei[E+e], 1);
}

__device__ __forceinline__ int wave_scan(int v, int lane){
    #pragma unroll
    for (int off=1; off<64; off<<=1){
        int t = __shfl_up(v, off, 64);
        if (lane >= off) v += t;
    }
    return v;
}

__global__ __launch_bounds__(1024) void k_scan1(const int* __restrict__ deg,
        int* __restrict__ excl, int* __restrict__ bsum, int N){
    __shared__ int ws[16];
    int i = blockIdx.x*1024 + threadIdx.x;
    int lane = threadIdx.x & 63, wid = threadIdx.x >> 6;
    int v = (i < N) ? deg[i] : 0;
    int inc = wave_scan(v, lane);
    if (lane == 63) ws[wid] = inc;
    __syncthreads();
    if (wid == 0){
        int wv = (lane < 16) ? ws[lane] : 0;
        int winc = wave_scan(wv, lane);
        if (lane < 16) ws[lane] = winc - wv;
    }
    __syncthreads();
    int off = ws[wid];
    if (i < N) excl[i] = off + inc - v;
    if (threadIdx.x == 1023) bsum[blockIdx.x] = off + inc;
}

__global__ void k_scan2(int* __restrict__ bsum, int nb){
    if (threadIdx.x == 0 && blockIdx.x == 0){
        int c = 0;
        for (int i = 0; i < nb; i++){ int t = bsum[i]; bsum[i] = c; c += t; }
    }
}

__global__ __launch_bounds__(256) void k_scan3(const int* __restrict__ excl,
        const int* __restrict__ bsum, int* __restrict__ rowptr,
        int* __restrict__ cursor, int N, int E){
    int i = blockIdx.x*256 + threadIdx.x;
    if (i < N){
        int r = excl[i] + bsum[i >> 10];
        rowptr[i] = r; cursor[i] = r;
    } else if (i == N){
        rowptr[N] = E;
    }
}

__global__ __launch_bounds__(256) void k_bucket(const int* __restrict__ ei, int E,
        int* __restrict__ cursor, int* __restrict__ csr){
    int e = blockIdx.x*256 + threadIdx.x;
    if (e >= E) return;
    int pos = atomicAdd(cursor + ei[E+e], 1);
    csr[pos] = ei[e];
}

// ---------------- GAT aggregation: lane-group edge parallelism,
// 2-slot ping-pong prefetch, fixed-upper-bound softmax, group-reduce per dst,
// non-temporal output stores, fused BN stats / decoder ----------------

template<int H, int C, bool STATS, bool DECODE>
__global__ __launch_bounds__(256) void k_gat_agg(
        const int* __restrict__ rowptr, const int* __restrict__ csr_src,
        const float* __restrict__ al_s, const float* __restrict__ al_d,
        const float* __restrict__ mh,
        const u16* __restrict__ hfeat, const float* __restrict__ b,
        float* __restrict__ z, float* __restrict__ cs, float* __restrict__ cq,
        const float* __restrict__ decW, const float* __restrict__ decb,
        float* __restrict__ out, int N, int totWaves)
{
    constexpr int M = H*C;
    constexpr int GS = M/8;        // lanes per edge (16 for M=128, 8 for M=64)
    constexpr int EPS = 64/GS;     // edges per slot == number of groups
    const int lane = threadIdx.x & 63;
    const int q = lane % GS;       // col-block index
    const int g = lane / GS;       // edge group
    const int col0 = q*8;
    const int hd = col0 / C;       // head (8 cols within one head; 8|C)
    const int gw = blockIdx.x*4 + (threadIdx.x >> 6);

    const float mhf = mh[hd];
    float bj[8];
    #pragma unroll
    for (int j=0;j<8;j++) bj[j] = b[col0+j];

    float w[8][4];
    if (DECODE){
        #pragma unroll
        for (int j=0;j<8;j++)
            #pragma unroll
            for (int o=0;o<4;o++) w[j][o] = decW[(col0+j)*4 + o];
    }
    float ls[8], lq[8];
    if (STATS){
        #pragma unroll
        for (int j=0;j<8;j++){ ls[j]=0.f; lq[j]=0.f; }
    }

    for (int dst = gw; dst < N; dst += totWaves){
        int p0 = rowptr[dst], p1 = rowptr[dst+1];     // issue early
        float ald = al_d[(size_t)dst*H + hd];
        float v0 = al_s[(size_t)dst*H + hd] + ald;
        v0 = v0 > 0.f ? v0 : LEAKY*v0;
        float tt = mhf + ald;
        float mb = tt > 0.f ? tt : LEAKY*tt;          // >= segment max
        mb = fminf(mb, v0 + 40.f);                    // keep s in normal range

        float ex0 = __expf(v0 - mb) * (1.0f/EPS);     // split self-loop across groups
        float s = ex0;
        float acc[8];
        ushort8 hd8 = *(const ushort8*)(hfeat + (size_t)dst*M + col0);
        #pragma unroll
        for (int j=0;j<8;j++) acc[j] = bf2f(hd8[j]) * ex0;

        auto LD = [&](int base, ushort8& hv, float& vs){
            int idx = base + g;
            int src = dst;
            if (idx < p1) src = csr_src[idx];         // predicated, in-bounds
            float t = al_s[(size_t)src*H + hd];
            vs = (idx < p1) ? t : -1e30f;             // masked-out -> ex = 0
            hv = *(const ushort8*)(hfeat + (size_t)src*M + col0);
        };
        auto PR = [&](const ushort8& hv, float vs){
            float vv = vs + ald;
            vv = vv > 0.f ? vv : LEAKY*vv;
            float ex = __expf(vv - mb);
            s += ex;
            #pragma unroll
            for (int j=0;j<8;j++) acc[j] = fmaf(bf2f(hv[j]), ex, acc[j]);
        };

        ushort8 hvA, hvB; float vsA=0.f, vsB=0.f;
        int p = p0;
        LD(p, hvA, vsA);
        while (p < p1){
            LD(p+EPS, hvB, vsB);
            PR(hvA, vsA);
            p += EPS;
            if (p >= p1) break;
            LD(p+EPS, hvA, vsA);
            PR(hvB, vsB);
            p += EPS;
        }

        // reduce across edge groups (lanes differing by multiples of GS)
        #pragma unroll
        for (int off = GS; off < 64; off <<= 1){
            s += __shfl_xor(s, off, 64);
            #pragma unroll
            for (int j=0;j<8;j++) acc[j] += __shfl_xor(acc[j], off, 64);
        }
        float inv = 1.f/s;
        float o8[8];
        #pragma unroll
        for (int j=0;j<8;j++) o8[j] = acc[j]*inv + bj[j];

        if (STATS){
            #pragma unroll
            for (int j=0;j<8;j++){ ls[j] += o8[j]; lq[j] += o8[j]*o8[j]; }
        }
        if (!DECODE){
            if (lane < GS){
                f32x4 w0v = {o8[0],o8[1],o8[2],o8[3]};
                f32x4 w1v = {o8[4],o8[5],o8[6],o8[7]};
                __builtin_nontemporal_store(w0v, (f32x4*)(z + (size_t)dst*M + col0));
                __builtin_nontemporal_store(w1v, (f32x4*)(z + (size_t)dst*M + col0 + 4));
            }
        } else {
            float p4[4] = {0.f,0.f,0.f,0.f};
            #pragma unroll
            for (int j=0;j<8;j++)
                #pragma unroll
                for (int o=0;o<4;o++) p4[o] = fmaf(o8[j], w[j][o], p4[o]);
            #pragma unroll
            for (int off=1; off<GS; off<<=1){
                #pragma unroll
                for (int o=0;o<4;o++) p4[o] += __shfl_xor(p4[o], off, 64);
            }
            if (lane == 0){
                f32x4 o = {p4[0]+decb[0], p4[1]+decb[1], p4[2]+decb[2], p4[3]+decb[3]};
                __builtin_nontemporal_store(o, (f32x4*)(out + (size_t)dst*4));
            }
        }
    }

    if (STATS){
        __shared__ float sls[128], slq[128];
        if (threadIdx.x < 128){ sls[threadIdx.x]=0.f; slq[threadIdx.x]=0.f; }
        __syncthreads();
        if (lane < GS){      // one copy per wave (stats identical across groups)
            #pragma unroll
            for (int j=0;j<8;j++){
                atomicAdd(&sls[col0+j], ls[j]);
                atomicAdd(&slq[col0+j], lq[j]);
            }
        }
        __syncthreads();
        if (threadIdx.x < 128){
            atomicAdd(cs + threadIdx.x, sls[threadIdx.x]);
            atomicAdd(cq + threadIdx.x, slq[threadIdx.x]);
        }
    }
}

extern "C" void kernel_launch(void* const* d_in, const int* in_sizes, int n_in,
                              void* d_out, int out_size, void* d_ws, size_t ws_size,
                              hipStream_t stream){
    const float* x      = (const float*)d_in[0];
    const int*   ei     = (const int*)  d_in[1];
    const float* enc_W  = (const float*)d_in[2];
    const float* enc_b  = (const float*)d_in[3];
    const float* in_W   = (const float*)d_in[4];
    const float* in_as  = (const float*)d_in[5];
    const float* in_ad  = (const float*)d_in[6];
    const float* in_b   = (const float*)d_in[7];
    const float* hid_W  = (const float*)d_in[8];
    const float* hid_as = (const float*)d_in[9];
    const float* hid_ad = (const float*)d_in[10];
    const float* hid_b  = (const float*)d_in[11];
    const float* bn_g   = (const float*)d_in[12];
    const float* bn_b   = (const float*)d_in[13];
    const float* out_W  = (const float*)d_in[14];
    const float* out_as = (const float*)d_in[15];
    const float* out_ad = (const float*)d_in[16];
    const float* out_b  = (const float*)d_in[17];
    const float* dec_W  = (const float*)d_in[18];
    const float* dec_b  = (const float*)d_in[19];

    const int N = in_sizes[0] / 7;
    const int E = in_sizes[1] / 2;
    const int NB = (N + 1023) / 1024;
    const int NT = (N + 63) / 64;
    const int AGG_BLOCKS = 2048, TOT_WAVES = AGG_BLOCKS*4;

    // workspace layout:
    float*    bufZ   = (float*)d_ws;                  // [N,128] fp32 activations
    float*    al_s   = bufZ + (size_t)N*128;          // [N,4]
    float*    al_d   = al_s + (size_t)N*4;            // [N,4]
    float*    cs     = al_d + (size_t)N*4;            // [128]
    float*    cq     = cs + 128;                      // [128]
    float*    mh     = cq + 128;                      // [8] per-head logit max
    float*    pm     = mh + 8;                        // [256] partial maxes
    float*    scale  = pm + 256;                      // [128]
    float*    shift  = scale + 128;                   // [128]
    int*      deg    = (int*)(shift + 128);           // [N]
    int*      excl   = deg + N;                       // [N]
    int*      rowptr = excl + N;                      // [N+1]
    int*      cursor = rowptr + (N+1);                // [N]
    int*      bsum   = cursor + N;                    // [NB]
    int*      csr    = bsum + NB;                     // [E]
    u16*      hb     = (u16*)(((uintptr_t)(csr + E) + 15) & ~(uintptr_t)15); // [N,128] bf16
    u16*      wk     = hb + (size_t)N*128;
    // packed weights incl. 16 augmented cols: strides 144 / 144 / 144 / 80
    u16* wk_in_hi  = wk;                     u16* wk_in_lo  = wk_in_hi  + 64*144;
    u16* wk_h0_hi  = wk_in_lo  + 64*144;     u16* wk_h0_lo  = wk_h0_hi  + 128*144;
    u16* wk_h1_hi  = wk_h0_lo  + 128*144;    u16* wk_h1_lo  = wk_h1_hi  + 128*144;
    u16* wk_out_hi = wk_h1_lo  + 128*144;    u16* wk_out_lo = wk_out_hi + 128*80;

    // ---- pack weights + augmented logit columns ----
    k_pack_w<64,128,144><<<(64*128+255)/256, 256, 0, stream>>>(in_W, wk_in_hi, wk_in_lo);
    k_pack_a<64,128,144,4,32><<<(64*16+255)/256, 256, 0, stream>>>(in_W, in_as, in_ad, wk_in_hi, wk_in_lo);
    k_pack_w<128,128,144><<<(128*128+255)/256, 256, 0, stream>>>(hid_W, wk_h0_hi, wk_h0_lo);
    k_pack_a<128,128,144,4,32><<<(128*16+255)/256, 256, 0, stream>>>(hid_W, hid_as, hid_ad, wk_h0_hi, wk_h0_lo);
    k_pack_w<128,128,144><<<(128*128+255)/256, 256, 0, stream>>>(hid_W + 128*128, wk_h1_hi, wk_h1_lo);
    k_pack_a<128,128,144,4,32><<<(128*16+255)/256, 256, 0, stream>>>(hid_W + 128*128, hid_as + 128, hid_ad + 128, wk_h1_hi, wk_h1_lo);
    k_pack_w<128,64,80><<<(128*64+255)/256, 256, 0, stream>>>(out_W, wk_out_hi, wk_out_lo);
    k_pack_a<128,64,80,1,64><<<(128*16+255)/256, 256, 0, stream>>>(out_W, out_as, out_ad, wk_out_hi, wk_out_lo);

    // ---- CSR build ----
    hipMemsetAsync(deg, 0, (size_t)N*sizeof(int), stream);
    k_deg   <<<(E+255)/256, 256, 0, stream>>>(ei, E, deg);
    k_scan1 <<<NB, 1024, 0, stream>>>(deg, excl, bsum, N);
    k_scan2 <<<1, 64, 0, stream>>>(bsum, NB);
    k_scan3 <<<(N+1+255)/256, 256, 0, stream>>>(excl, bsum, rowptr, cursor, N, E);
    k_bucket<<<(E+255)/256, 256, 0, stream>>>(ei, E, cursor, csr);

    // ---- encoder ----
    k_encoder<<<(N*64+255)/256, 256, 0, stream>>>(x, enc_W, enc_b, bufZ, N);

    const float invN = 1.f/(float)N;

    // ---- GAT layer 1 (K=64, no input BN) ----
    hipMemsetAsync(cs, 0, 256*sizeof(float), stream);
    k_gemm<64,128,2,2,2,4,4,false><<<NT, 256, 0, stream>>>(bufZ, wk_in_hi, wk_in_lo,
            nullptr, nullptr, hb, al_s, al_d, N);
    k_mh1<4><<<64, 256, 0, stream>>>(al_s, pm, N*4);
    k_mh2<4><<<1, 64, 0, stream>>>(pm, mh);
    k_gat_agg<4,32,true,false><<<AGG_BLOCKS, 256, 0, stream>>>(rowptr, csr, al_s, al_d, mh,
            hb, in_b, bufZ, cs, cq, nullptr, nullptr, nullptr, N, TOT_WAVES);
    k_bn_coef<<<1, 128, 0, stream>>>(cs, cq, bn_g, bn_b, scale, shift, invN);

    // ---- hidden GAT layers (input BN+ReLU fused into GEMM staging) ----
    for (int i = 0; i < 2; i++){
        const u16* whi = i ? wk_h1_hi : wk_h0_hi;
        const u16* wlo = i ? wk_h1_lo : wk_h0_lo;
        hipMemsetAsync(cs, 0, 256*sizeof(float), stream);
        k_gemm<128,128,2,2,2,4,4,true><<<NT, 256, 0, stream>>>(bufZ, whi, wlo,
                scale, shift, hb, al_s, al_d, N);
        k_mh1<4><<<64, 256, 0, stream>>>(al_s, pm, N*4);
        k_mh2<4><<<1, 64, 0, stream>>>(pm, mh);
        k_gat_agg<4,32,true,false><<<AGG_BLOCKS, 256, 0, stream>>>(rowptr, csr, al_s, al_d, mh,
                hb, hid_b + (size_t)i*128, bufZ, cs, cq, nullptr, nullptr, nullptr, N, TOT_WAVES);
        k_bn_coef<<<1, 128, 0, stream>>>(cs, cq, bn_g + (i+1)*128, bn_b + (i+1)*128, scale, shift, invN);
    }

    // ---- out GAT layer (K=128 -> 1x64) + fused decoder ----
    k_gemm<128,64,4,1,1,4,1,true><<<NT, 256, 0, stream>>>(bufZ, wk_out_hi, wk_out_lo,
            scale, shift, hb, al_s, al_d, N);
    k_mh1<1><<<64, 256, 0, stream>>>(al_s, pm, N);
    k_mh2<1><<<1, 64, 0, stream>>>(pm, mh);
    k_gat_agg<1,64,false,true><<<AGG_BLOCKS, 256, 0, stream>>>(rowptr, csr, al_s, al_d, mh,
            hb, out_b, nullptr, nullptr, nullptr, dec_W, dec_b, (float*)d_out, N, TOT_WAVES);
}

// Round 14
// 928.291 us; speedup vs baseline: 1.0175x; 1.0175x over previous
//
#include <hip/hip_runtime.h>
#include <math.h>

#define LEAKY 0.2f
#define BN_EPS 1e-5f

typedef unsigned short u16;
typedef __bf16 bf16x8 __attribute__((ext_vector_type(8)));
typedef float f32x4 __attribute__((ext_vector_type(4)));
typedef u16 ushort8 __attribute__((ext_vector_type(8)));

__device__ __forceinline__ u16 f2bf(float x){
    unsigned u = __float_as_uint(x);
    u += 0x7FFFu + ((u >> 16) & 1u);          // RNE (finite data, no NaN)
    return (u16)(u >> 16);
}
__device__ __forceinline__ float bf2f(u16 b){ return __uint_as_float(((unsigned)b) << 16); }

// monotone float<->uint encoding for (LDS) atomicMax on floats
__device__ __forceinline__ unsigned enc_ord(float x){
    unsigned u = __float_as_uint(x);
    return (u & 0x80000000u) ? ~u : (u | 0x80000000u);
}
__device__ __forceinline__ float dec_ord(unsigned u){
    unsigned b = (u & 0x80000000u) ? (u ^ 0x80000000u) : ~u;
    return __uint_as_float(b);
}

// pack W[K][MW] fp32 -> hi/lo bf16 in MFMA B-fragment layout with MT col stride
template<int K, int MW, int MT>
__global__ __launch_bounds__(256) void k_pack_w(const float* __restrict__ W,
        u16* __restrict__ hi, u16* __restrict__ lo){
    int idx = blockIdx.x*256 + threadIdx.x;
    if (idx >= K*MW) return;
    int e = idx & 7, l16 = (idx >> 3) & 3, rest = idx >> 5;
    int n = rest % MW, t = rest / MW;
    int k = t*32 + l16*8 + e;
    float w = W[(size_t)k*MW + n];
    u16 hb = f2bf(w);
    size_t o = ((size_t)(t*MT + n)*4 + (size_t)l16)*8 + e;
    hi[o] = hb;
    lo[o] = f2bf(w - bf2f(hb));
}

// pack augmented attention columns: col MW+j (j<2H) = W[:,head block] . a_{src|dst}
template<int K, int MW, int MT, int H, int C>
__global__ __launch_bounds__(256) void k_pack_a(const float* __restrict__ W,
        const float* __restrict__ as, const float* __restrict__ ad,
        u16* __restrict__ hi, u16* __restrict__ lo){
    int idx = blockIdx.x*256 + threadIdx.x;
    if (idx >= K*16) return;
    int e = idx & 7, l16 = (idx >> 3) & 3, rest = idx >> 5;
    int j = rest % 16, t = rest / 16;
    int k = t*32 + l16*8 + e;
    float v = 0.f;
    if (j < 2*H){
        int hh = j >> 1;
        const float* a = (j & 1) ? ad : as;
        for (int c = 0; c < C; c++)
            v += W[(size_t)k*MW + hh*C + c] * a[hh*C + c];
    }
    u16 hb = f2bf(v);
    size_t o = ((size_t)(t*MT + MW + j)*4 + (size_t)l16)*8 + e;
    hi[o] = hb;
    lo[o] = f2bf(v - bf2f(hb));
}

// BN coefs: scale = gamma*rsqrt(var+eps); shift = beta - mu*scale
__global__ void k_bn_coef(const float* __restrict__ cs, const float* __restrict__ cq,
        const float* __restrict__ g, const float* __restrict__ be,
        float* __restrict__ scale, float* __restrict__ shift, float invN){
    int j = threadIdx.x;   // 128
    float mu = cs[j]*invN;
    float var = cq[j]*invN - mu*mu;
    float s = g[j]*rsqrtf(var + BN_EPS);
    scale[j] = s; shift[j] = be[j] - mu*s;
}

// single-block reduction of per-GEMM-block partial maxes -> mh[H]
template<int H>
__global__ void k_mh2b(const float* __restrict__ pm, float* __restrict__ mh, int total){
    int t = threadIdx.x;      // 256 threads; 256 % H == 0 so i%H == t%H
    float m = -1e30f;
    for (int i = t; i < total; i += 256) m = fmaxf(m, pm[i]);
    #pragma unroll
    for (int off = H; off < 64; off <<= 1)
        m = fmaxf(m, __shfl_xor(m, off, 64));
    __shared__ float ws[16];
    int lane = t & 63, wid = t >> 6;
    if (lane < H) ws[wid*H + lane] = m;
    __syncthreads();
    if (t < H){
        float mm = ws[t];
        #pragma unroll
        for (int w = 1; w < 4; w++) mm = fmaxf(mm, ws[w*H + t]);
        mh[t] = mm;
    }
}

// split-bf16 MFMA GEMM; optional fused encoder (x@encW+b on staging) or fused
// input-BN+ReLU; attention logits via augmented B columns; per-block partial
// max of al_s -> pm (plain store, no global atomics); writes h as bf16.
template<int K, int MW, int RW, int CW, int WR, int WC, int H, bool BNIN, bool ENC>
__global__ __launch_bounds__(256) void k_gemm(const float* __restrict__ z,
        const u16* __restrict__ Whi, const u16* __restrict__ Wlo,
        const float* __restrict__ bnscale, const float* __restrict__ bnshift,
        const float* __restrict__ x, const float* __restrict__ encW,
        const float* __restrict__ encb,
        u16* __restrict__ hout, float* __restrict__ al_s, float* __restrict__ al_d,
        float* __restrict__ pm, int N)
{
    static_assert(RW*CW == 4 && RW*WR*16 == 64 && CW*WC*16 == MW, "tile config");
    constexpr int MT = MW + 16;    // packed stride incl. augmented cols
    constexpr int KS = K/32;
    constexpr int KG = K/8;
    __shared__ __align__(16) u16 Ahi[64*K];
    __shared__ __align__(16) u16 Alo[64*K];
    __shared__ unsigned smax[H];
    __shared__ float sEnc[ENC ? 7*64 + 64 : 1];
    const int brow = blockIdx.x*64;
    const int tid = threadIdx.x;

    if (ENC){
        for (int i = tid; i < 7*64; i += 256) sEnc[i] = encW[i];
        if (tid < 64) sEnc[7*64 + tid] = encb[tid];
        __syncthreads();
    }
    if (tid < H) smax[tid] = 0;    // enc_ord-monotone lower bound

    for (int u = tid; u < 64*KG; u += 256){
        int row = u / KG, kg = u % KG;
        int gr = brow + row;
        float v[8];
        if (gr < N){
            if (ENC){
                float xr[7];
                #pragma unroll
                for (int k=0;k<7;k++) xr[k] = x[(size_t)gr*7 + k];
                #pragma unroll
                for (int e=0;e<8;e++){
                    int j = kg*8 + e;
                    float a = sEnc[7*64 + j];
                    #pragma unroll
                    for (int k=0;k<7;k++) a = fmaf(xr[k], sEnc[k*64 + j], a);
                    v[e] = a;
                }
            } else {
                const float4* p = (const float4*)(z + (size_t)gr*K + kg*8);
                float4 a = p[0], bq = p[1];
                v[0]=a.x; v[1]=a.y; v[2]=a.z; v[3]=a.w;
                v[4]=bq.x; v[5]=bq.y; v[6]=bq.z; v[7]=bq.w;
                if (BNIN){
                    const float4* sc = (const float4*)(bnscale + kg*8);
                    const float4* sh = (const float4*)(bnshift + kg*8);
                    float4 s0=sc[0], s1=sc[1], t0=sh[0], t1=sh[1];
                    v[0]=fmaxf(fmaf(v[0],s0.x,t0.x),0.f);
                    v[1]=fmaxf(fmaf(v[1],s0.y,t0.y),0.f);
                    v[2]=fmaxf(fmaf(v[2],s0.z,t0.z),0.f);
                    v[3]=fmaxf(fmaf(v[3],s0.w,t0.w),0.f);
                    v[4]=fmaxf(fmaf(v[4],s1.x,t1.x),0.f);
                    v[5]=fmaxf(fmaf(v[5],s1.y,t1.y),0.f);
                    v[6]=fmaxf(fmaf(v[6],s1.z,t1.z),0.f);
                    v[7]=fmaxf(fmaf(v[7],s1.w,t1.w),0.f);
                }
            }
        } else {
            #pragma unroll
            for (int e=0;e<8;e++) v[e]=0.f;
        }
        ushort8 h8, l8;
        #pragma unroll
        for (int e=0;e<8;e++){
            u16 hb = f2bf(v[e]);
            h8[e] = hb;
            l8[e] = f2bf(v[e] - bf2f(hb));
        }
        int rb = row >> 4, t = kg >> 2, lg = kg & 3;
        int gidx = (rb*KS + t)*64 + (row & 15) + 16*lg;
        gidx ^= (gidx >> 4) & 7;                 // bank-conflict swizzle
        *(ushort8*)&Ahi[gidx*8] = h8;
        *(ushort8*)&Alo[gidx*8] = l8;
    }
    __syncthreads();

    const int wave = tid >> 6, lane = tid & 63;
    const int wrow = wave / CW, wcol = wave % CW;
    const int l15 = lane & 15, l16 = lane >> 4;

    f32x4 acc[WR][WC];
    f32x4 acc_e[WR];
    #pragma unroll
    for (int r=0;r<WR;r++){
        acc_e[r] = (f32x4){0.f,0.f,0.f,0.f};
        #pragma unroll
        for (int c=0;c<WC;c++) acc[r][c] = (f32x4){0.f,0.f,0.f,0.f};
    }

    #pragma unroll
    for (int t = 0; t < KS; ++t){
        bf16x8 ah[WR], al[WR];
        #pragma unroll
        for (int r=0;r<WR;r++){
            int rb = wrow*WR + r;
            int goff = (rb*KS + t)*64 + lane;
            goff ^= (goff >> 4) & 7;             // matching swizzle
            ah[r] = *(const bf16x8*)&Ahi[goff*8];
            al[r] = *(const bf16x8*)&Alo[goff*8];
        }
        bf16x8 bh[WC], bl[WC];
        #pragma unroll
        for (int c=0;c<WC;c++){
            int n = (wcol*WC + c)*16 + l15;
            size_t off = ((size_t)(t*MT + n)*4 + (size_t)l16)*8;
            bh[c] = *(const bf16x8*)&Whi[off];
            bl[c] = *(const bf16x8*)&Wlo[off];
        }
        #pragma unroll
        for (int r=0;r<WR;r++)
            #pragma unroll
            for (int c=0;c<WC;c++){
                acc[r][c] = __builtin_amdgcn_mfma_f32_16x16x32_bf16(al[r], bh[c], acc[r][c], 0,0,0);
                acc[r][c] = __builtin_amdgcn_mfma_f32_16x16x32_bf16(ah[r], bl[c], acc[r][c], 0,0,0);
                acc[r][c] = __builtin_amdgcn_mfma_f32_16x16x32_bf16(ah[r], bh[c], acc[r][c], 0,0,0);
            }
        if (wcol == 0){                           // augmented logit columns
            size_t offE = ((size_t)(t*MT + MW + l15)*4 + (size_t)l16)*8;
            bf16x8 bhe = *(const bf16x8*)&Whi[offE];
            bf16x8 ble = *(const bf16x8*)&Wlo[offE];
            #pragma unroll
            for (int r=0;r<WR;r++){
                acc_e[r] = __builtin_amdgcn_mfma_f32_16x16x32_bf16(al[r], bhe, acc_e[r], 0,0,0);
                acc_e[r] = __builtin_amdgcn_mfma_f32_16x16x32_bf16(ah[r], ble, acc_e[r], 0,0,0);
                acc_e[r] = __builtin_amdgcn_mfma_f32_16x16x32_bf16(ah[r], bhe, acc_e[r], 0,0,0);
            }
        }
    }

    // logits: lane l15 = j holds the complete dot for its rows — direct store;
    // also fold per-block al_s max into LDS (no global atomics)
    if (wcol == 0 && l15 < 2*H){
        int j = l15;
        float wm = -1e30f;
        #pragma unroll
        for (int r=0;r<WR;r++)
            #pragma unroll
            for (int q=0;q<4;q++){
                int rowg = brow + (wrow*WR + r)*16 + l16*4 + q;
                if (rowg < N){
                    float v = acc_e[r][q];
                    if (H==4){
                        if (j & 1) al_d[(size_t)rowg*4 + (j>>1)] = v;
                        else       al_s[(size_t)rowg*4 + (j>>1)] = v;
                    } else {
                        if (j & 1) al_d[rowg] = v;
                        else       al_s[rowg] = v;
                    }
                }
                if (!(j & 1)) wm = fmaxf(wm, acc_e[r][q]);
            }
        if (!(j & 1)){
            wm = fmaxf(wm, __shfl_xor(wm, 16, 64));
            wm = fmaxf(wm, __shfl_xor(wm, 32, 64));
            if (l16 == 0) atomicMax(&smax[j>>1], enc_ord(wm));
        }
    }

    // h write (bf16)
    #pragma unroll
    for (int r=0;r<WR;r++)
        #pragma unroll
        for (int c=0;c<WC;c++){
            int colg = (wcol*WC + c)*16 + l15;
            #pragma unroll
            for (int q=0;q<4;q++){
                int rowg = brow + (wrow*WR + r)*16 + l16*4 + q;
                if (rowg < N) hout[(size_t)rowg*MW + colg] = f2bf(acc[r][c][q]);
            }
        }

    __syncthreads();
    if (tid < H) pm[(size_t)blockIdx.x*H + tid] = dec_ord(smax[tid]);
}

// ---------------- CSR build (once per call) ----------------

__global__ __launch_bounds__(256) void k_deg(const int* __restrict__ ei, int E,
        int* __restrict__ deg){
    int e = blockIdx.x*256 + threadIdx.x;
    if (e < E) atomicAdd(deg + ei[E+e], 1);
}

__device__ __forceinline__ int wave_scan(int v, int lane){
    #pragma unroll
    for (int off=1; off<64; off<<=1){
        int t = __shfl_up(v, off, 64);
        if (lane >= off) v += t;
    }
    return v;
}

__global__ __launch_bounds__(1024) void k_scan1(const int* __restrict__ deg,
        int* __restrict__ excl, int* __restrict__ bsum, int N){
    __shared__ int ws[16];
    int i = blockIdx.x*1024 + threadIdx.x;
    int lane = threadIdx.x & 63, wid = threadIdx.x >> 6;
    int v = (i < N) ? deg[i] : 0;
    int inc = wave_scan(v, lane);
    if (lane == 63) ws[wid] = inc;
    __syncthreads();
    if (wid == 0){
        int wv = (lane < 16) ? ws[lane] : 0;
        int winc = wave_scan(wv, lane);
        if (lane < 16) ws[lane] = winc - wv;
    }
    __syncthreads();
    int off = ws[wid];
    if (i < N) excl[i] = off + inc - v;
    if (threadIdx.x == 1023) bsum[blockIdx.x] = off + inc;
}

__global__ void k_scan2(int* __restrict__ bsum, int nb){
    if (threadIdx.x == 0 && blockIdx.x == 0){
        int c = 0;
        for (int i = 0; i < nb; i++){ int t = bsum[i]; bsum[i] = c; c += t; }
    }
}

__global__ __launch_bounds__(256) void k_scan3(const int* __restrict__ excl,
        const int* __restrict__ bsum, int* __restrict__ rowptr,
        int* __restrict__ cursor, int N, int E){
    int i = blockIdx.x*256 + threadIdx.x;
    if (i < N){
        int r = excl[i] + bsum[i >> 10];
        rowptr[i] = r; cursor[i] = r;
    } else if (i == N){
        rowptr[N] = E;
    }
}

__global__ __launch_bounds__(256) void k_bucket(const int* __restrict__ ei, int E,
        int* __restrict__ cursor, int* __restrict__ csr){
    int e = blockIdx.x*256 + threadIdx.x;
    if (e >= E) return;
    int pos = atomicAdd(cursor + ei[E+e], 1);
    csr[pos] = ei[e];
}

// ---------------- GAT aggregation: lane-group edge parallelism,
// 2-slot ping-pong prefetch, fixed-upper-bound softmax, group-reduce per dst,
// non-temporal output stores, fused BN stats / decoder ----------------

template<int H, int C, bool STATS, bool DECODE>
__global__ __launch_bounds__(256) void k_gat_agg(
        const int* __restrict__ rowptr, const int* __restrict__ csr_src,
        const float* __restrict__ al_s, const float* __restrict__ al_d,
        const float* __restrict__ mh,
        const u16* __restrict__ hfeat, const float* __restrict__ b,
        float* __restrict__ z, float* __restrict__ cs, float* __restrict__ cq,
        const float* __restrict__ decW, const float* __restrict__ decb,
        float* __restrict__ out, int N, int totWaves)
{
    constexpr int M = H*C;
    constexpr int GS = M/8;        // lanes per edge (16 for M=128, 8 for M=64)
    constexpr int EPS = 64/GS;     // edges per slot == number of groups
    const int lane = threadIdx.x & 63;
    const int q = lane % GS;       // col-block index
    const int g = lane / GS;       // edge group
    const int col0 = q*8;
    const int hd = col0 / C;       // head (8 cols within one head; 8|C)
    const int gw = blockIdx.x*4 + (threadIdx.x >> 6);

    const float mhf = mh[hd];
    float bj[8];
    #pragma unroll
    for (int j=0;j<8;j++) bj[j] = b[col0+j];

    float w[8][4];
    if (DECODE){
        #pragma unroll
        for (int j=0;j<8;j++)
            #pragma unroll
            for (int o=0;o<4;o++) w[j][o] = decW[(col0+j)*4 + o];
    }
    float ls[8], lq[8];
    if (STATS){
        #pragma unroll
        for (int j=0;j<8;j++){ ls[j]=0.f; lq[j]=0.f; }
    }

    for (int dst = gw; dst < N; dst += totWaves){
        int p0 = rowptr[dst], p1 = rowptr[dst+1];     // issue early
        float ald = al_d[(size_t)dst*H + hd];
        float v0 = al_s[(size_t)dst*H + hd] + ald;
        v0 = v0 > 0.f ? v0 : LEAKY*v0;
        float tt = mhf + ald;
        float mb = tt > 0.f ? tt : LEAKY*tt;          // >= segment max
        mb = fminf(mb, v0 + 40.f);                    // keep s in normal range

        float ex0 = __expf(v0 - mb) * (1.0f/EPS);     // split self-loop across groups
        float s = ex0;
        float acc[8];
        ushort8 hd8 = *(const ushort8*)(hfeat + (size_t)dst*M + col0);
        #pragma unroll
        for (int j=0;j<8;j++) acc[j] = bf2f(hd8[j]) * ex0;

        auto LD = [&](int base, ushort8& hv, float& vs){
            int idx = base + g;
            int src = dst;
            if (idx < p1) src = csr_src[idx];         // predicated, in-bounds
            float t = al_s[(size_t)src*H + hd];
            vs = (idx < p1) ? t : -1e30f;             // masked-out -> ex = 0
            hv = *(const ushort8*)(hfeat + (size_t)src*M + col0);
        };
        auto PR = [&](const ushort8& hv, float vs){
            float vv = vs + ald;
            vv = vv > 0.f ? vv : LEAKY*vv;
            float ex = __expf(vv - mb);
            s += ex;
            #pragma unroll
            for (int j=0;j<8;j++) acc[j] = fmaf(bf2f(hv[j]), ex, acc[j]);
        };

        ushort8 hvA, hvB; float vsA=0.f, vsB=0.f;
        int p = p0;
        LD(p, hvA, vsA);
        while (p < p1){
            LD(p+EPS, hvB, vsB);
            PR(hvA, vsA);
            p += EPS;
            if (p >= p1) break;
            LD(p+EPS, hvA, vsA);
            PR(hvB, vsB);
            p += EPS;
        }

        // reduce across edge groups (lanes differing by multiples of GS)
        #pragma unroll
        for (int off = GS; off < 64; off <<= 1){
            s += __shfl_xor(s, off, 64);
            #pragma unroll
            for (int j=0;j<8;j++) acc[j] += __shfl_xor(acc[j], off, 64);
        }
        float inv = 1.f/s;
        float o8[8];
        #pragma unroll
        for (int j=0;j<8;j++) o8[j] = acc[j]*inv + bj[j];

        if (STATS){
            #pragma unroll
            for (int j=0;j<8;j++){ ls[j] += o8[j]; lq[j] += o8[j]*o8[j]; }
        }
        if (!DECODE){
            if (lane < GS){
                f32x4 w0v = {o8[0],o8[1],o8[2],o8[3]};
                f32x4 w1v = {o8[4],o8[5],o8[6],o8[7]};
                __builtin_nontemporal_store(w0v, (f32x4*)(z + (size_t)dst*M + col0));
                __builtin_nontemporal_store(w1v, (f32x4*)(z + (size_t)dst*M + col0 + 4));
            }
        } else {
            float p4[4] = {0.f,0.f,0.f,0.f};
            #pragma unroll
            for (int j=0;j<8;j++)
                #pragma unroll
                for (int o=0;o<4;o++) p4[o] = fmaf(o8[j], w[j][o], p4[o]);
            #pragma unroll
            for (int off=1; off<GS; off<<=1){
                #pragma unroll
                for (int o=0;o<4;o++) p4[o] += __shfl_xor(p4[o], off, 64);
            }
            if (lane == 0){
                f32x4 o = {p4[0]+decb[0], p4[1]+decb[1], p4[2]+decb[2], p4[3]+decb[3]};
                __builtin_nontemporal_store(o, (f32x4*)(out + (size_t)dst*4));
            }
        }
    }

    if (STATS){
        __shared__ float sls[128], slq[128];
        if (threadIdx.x < 128){ sls[threadIdx.x]=0.f; slq[threadIdx.x]=0.f; }
        __syncthreads();
        if (lane < GS){      // one copy per wave (stats identical across groups)
            #pragma unroll
            for (int j=0;j<8;j++){
                atomicAdd(&sls[col0+j], ls[j]);
                atomicAdd(&slq[col0+j], lq[j]);
            }
        }
        __syncthreads();
        if (threadIdx.x < 128){
            atomicAdd(cs + threadIdx.x, sls[threadIdx.x]);
            atomicAdd(cq + threadIdx.x, slq[threadIdx.x]);
        }
    }
}

extern "C" void kernel_launch(void* const* d_in, const int* in_sizes, int n_in,
                              void* d_out, int out_size, void* d_ws, size_t ws_size,
                              hipStream_t stream){
    const float* x      = (const float*)d_in[0];
    const int*   ei     = (const int*)  d_in[1];
    const float* enc_W  = (const float*)d_in[2];
    const float* enc_b  = (const float*)d_in[3];
    const float* in_W   = (const float*)d_in[4];
    const float* in_as  = (const float*)d_in[5];
    const float* in_ad  = (const float*)d_in[6];
    const float* in_b   = (const float*)d_in[7];
    const float* hid_W  = (const float*)d_in[8];
    const float* hid_as = (const float*)d_in[9];
    const float* hid_ad = (const float*)d_in[10];
    const float* hid_b  = (const float*)d_in[11];
    const float* bn_g   = (const float*)d_in[12];
    const float* bn_b   = (const float*)d_in[13];
    const float* out_W  = (const float*)d_in[14];
    const float* out_as = (const float*)d_in[15];
    const float* out_ad = (const float*)d_in[16];
    const float* out_b  = (const float*)d_in[17];
    const float* dec_W  = (const float*)d_in[18];
    const float* dec_b  = (const float*)d_in[19];

    const int N = in_sizes[0] / 7;
    const int E = in_sizes[1] / 2;
    const int NB = (N + 1023) / 1024;
    const int NT = (N + 63) / 64;
    const int AGG_BLOCKS = 2048, TOT_WAVES = AGG_BLOCKS*4;

    // workspace layout:
    float*    bufZ   = (float*)d_ws;                  // [N,128] fp32 activations
    float*    al_s   = bufZ + (size_t)N*128;          // [N,4]
    float*    al_d   = al_s + (size_t)N*4;            // [N,4]
    float*    cs     = al_d + (size_t)N*4;            // [128]
    float*    cq     = cs + 128;                      // [128]
    float*    mh     = cq + 128;                      // [8] per-head logit max
    float*    pm     = mh + 8;                        // [NT*4] partial maxes
    float*    scale  = pm + 8192;                     // [128]
    float*    shift  = scale + 128;                   // [128]
    int*      deg    = (int*)(shift + 128);           // [N]
    int*      excl   = deg + N;                       // [N]
    int*      rowptr = excl + N;                      // [N+1]
    int*      cursor = rowptr + (N+1);                // [N]
    int*      bsum   = cursor + N;                    // [NB]
    int*      csr    = bsum + NB;                     // [E]
    u16*      hb     = (u16*)(((uintptr_t)(csr + E) + 15) & ~(uintptr_t)15); // [N,128] bf16
    u16*      wk     = hb + (size_t)N*128;
    // packed weights incl. 16 augmented cols: strides 144 / 144 / 144 / 80
    u16* wk_in_hi  = wk;                     u16* wk_in_lo  = wk_in_hi  + 64*144;
    u16* wk_h0_hi  = wk_in_lo  + 64*144;     u16* wk_h0_lo  = wk_h0_hi  + 128*144;
    u16* wk_h1_hi  = wk_h0_lo  + 128*144;    u16* wk_h1_lo  = wk_h1_hi  + 128*144;
    u16* wk_out_hi = wk_h1_lo  + 128*144;    u16* wk_out_lo = wk_out_hi + 128*80;

    // ---- pack weights + augmented logit columns ----
    k_pack_w<64,128,144><<<(64*128+255)/256, 256, 0, stream>>>(in_W, wk_in_hi, wk_in_lo);
    k_pack_a<64,128,144,4,32><<<(64*16+255)/256, 256, 0, stream>>>(in_W, in_as, in_ad, wk_in_hi, wk_in_lo);
    k_pack_w<128,128,144><<<(128*128+255)/256, 256, 0, stream>>>(hid_W, wk_h0_hi, wk_h0_lo);
    k_pack_a<128,128,144,4,32><<<(128*16+255)/256, 256, 0, stream>>>(hid_W, hid_as, hid_ad, wk_h0_hi, wk_h0_lo);
    k_pack_w<128,128,144><<<(128*128+255)/256, 256, 0, stream>>>(hid_W + 128*128, wk_h1_hi, wk_h1_lo);
    k_pack_a<128,128,144,4,32><<<(128*16+255)/256, 256, 0, stream>>>(hid_W + 128*128, hid_as + 128, hid_ad + 128, wk_h1_hi, wk_h1_lo);
    k_pack_w<128,64,80><<<(128*64+255)/256, 256, 0, stream>>>(out_W, wk_out_hi, wk_out_lo);
    k_pack_a<128,64,80,1,64><<<(128*16+255)/256, 256, 0, stream>>>(out_W, out_as, out_ad, wk_out_hi, wk_out_lo);

    // ---- CSR build ----
    hipMemsetAsync(deg, 0, (size_t)N*sizeof(int), stream);
    k_deg   <<<(E+255)/256, 256, 0, stream>>>(ei, E, deg);
    k_scan1 <<<NB, 1024, 0, stream>>>(deg, excl, bsum, N);
    k_scan2 <<<1, 64, 0, stream>>>(bsum, NB);
    k_scan3 <<<(N+1+255)/256, 256, 0, stream>>>(excl, bsum, rowptr, cursor, N, E);
    k_bucket<<<(E+255)/256, 256, 0, stream>>>(ei, E, cursor, csr);

    const float invN = 1.f/(float)N;

    // ---- GAT layer 1 (fused encoder in staging, K=64) ----
    hipMemsetAsync(cs, 0, 256*sizeof(float), stream);
    k_gemm<64,128,2,2,2,4,4,false,true><<<NT, 256, 0, stream>>>(bufZ, wk_in_hi, wk_in_lo,
            nullptr, nullptr, x, enc_W, enc_b, hb, al_s, al_d, pm, N);
    k_mh2b<4><<<1, 256, 0, stream>>>(pm, mh, NT*4);
    k_gat_agg<4,32,true,false><<<AGG_BLOCKS, 256, 0, stream>>>(rowptr, csr, al_s, al_d, mh,
            hb, in_b, bufZ, cs, cq, nullptr, nullptr, nullptr, N, TOT_WAVES);
    k_bn_coef<<<1, 128, 0, stream>>>(cs, cq, bn_g, bn_b, scale, shift, invN);

    // ---- hidden GAT layers (input BN+ReLU fused into GEMM staging) ----
    for (int i = 0; i < 2; i++){
        const u16* whi = i ? wk_h1_hi : wk_h0_hi;
        const u16* wlo = i ? wk_h1_lo : wk_h0_lo;
        hipMemsetAsync(cs, 0, 256*sizeof(float), stream);
        k_gemm<128,128,2,2,2,4,4,true,false><<<NT, 256, 0, stream>>>(bufZ, whi, wlo,
                scale, shift, nullptr, nullptr, nullptr, hb, al_s, al_d, pm, N);
        k_mh2b<4><<<1, 256, 0, stream>>>(pm, mh, NT*4);
        k_gat_agg<4,32,true,false><<<AGG_BLOCKS, 256, 0, stream>>>(rowptr, csr, al_s, al_d, mh,
                hb, hid_b + (size_t)i*128, bufZ, cs, cq, nullptr, nullptr, nullptr, N, TOT_WAVES);
        k_bn_coef<<<1, 128, 0, stream>>>(cs, cq, bn_g + (i+1)*128, bn_b + (i+1)*128, scale, shift, invN);
    }

    // ---- out GAT layer (K=128 -> 1x64) + fused decoder ----
    k_gemm<128,64,4,1,1,4,1,true,false><<<NT, 256, 0, stream>>>(bufZ, wk_out_hi, wk_out_lo,
            scale, shift, nullptr, nullptr, nullptr, hb, al_s, al_d, pm, N);
    k_mh2b<1><<<1, 256, 0, stream>>>(pm, mh, NT);
    k_gat_agg<1,64,false,true><<<AGG_BLOCKS, 256, 0, stream>>>(rowptr, csr, al_s, al_d, mh,
            hb, out_b, nullptr, nullptr, nullptr, dec_W, dec_b, (float*)d_out, N, TOT_WAVES);
}